// Round 16
// baseline (583.600 us; speedup 1.0000x reference)
//
#include <hip/hip_runtime.h>
#include <hip/hip_fp16.h>
#include <math.h>

#define NN 100000
#define EE 1600000
#define CC 20
#define DD 8
#define GG 1024
#define LL 2
#define KK (2*CC+DD)   // 48
#define EPSV 1e-5f

#define SCAN_TPB 256
#define SCAN_ELEMS 4
#define NB 98                      // ceil(NN / 1024)
#define NPAD (NB * SCAN_TPB * SCAN_ELEMS)  // 100352
#define RSTRIDE 8                  // record = 8 dwords = 32 B {s,d, 8×half, pad}
#define EPT 8                      // edges per thread in k_msg (EE/EPT % 64 == 0)

union H2U { __half2 h; unsigned int u; };

// native clang vector types for nontemporal builtins (HIP float4/int4 are rejected)
typedef float nf4 __attribute__((ext_vector_type(4)));
typedef int   ni4 __attribute__((ext_vector_type(4)));

// ---------------- CSR build ----------------
__global__ __launch_bounds__(256) void k_hist(const int* __restrict__ ei,
                                              int* __restrict__ cnt) {
    int t = blockIdx.x * 256 + threadIdx.x;
    if (t * 4 >= EE) return;
    ni4 d4 = __builtin_nontemporal_load(reinterpret_cast<const ni4*>(ei + EE) + t);
    atomicAdd(&cnt[d4.x], 1);
    atomicAdd(&cnt[d4.y], 1);
    atomicAdd(&cnt[d4.z], 1);
    atomicAdd(&cnt[d4.w], 1);
}

__global__ __launch_bounds__(SCAN_TPB) void k_scan_a(const int* __restrict__ cnt,
                                                     int* __restrict__ offs,
                                                     int* __restrict__ bsum) {
    __shared__ int sdata[SCAN_TPB];
    int base = blockIdx.x * (SCAN_TPB * SCAN_ELEMS) + threadIdx.x * SCAN_ELEMS;
    int v[SCAN_ELEMS];
    int tot = 0;
#pragma unroll
    for (int i = 0; i < SCAN_ELEMS; ++i) {
        int idx = base + i;
        v[i] = (idx < NN) ? cnt[idx] : 0;
        tot += v[i];
    }
    sdata[threadIdx.x] = tot;
    __syncthreads();
    for (int o = 1; o < SCAN_TPB; o <<= 1) {
        int t = (threadIdx.x >= o) ? sdata[threadIdx.x - o] : 0;
        __syncthreads();
        sdata[threadIdx.x] += t;
        __syncthreads();
    }
    int run = sdata[threadIdx.x] - tot;  // exclusive prefix of this thread
#pragma unroll
    for (int i = 0; i < SCAN_ELEMS; ++i) {
        offs[base + i] = run;
        run += v[i];
    }
    if (threadIdx.x == SCAN_TPB - 1) bsum[blockIdx.x] = sdata[threadIdx.x];
}

// scan of bsum (redundant per block) + add to offs; also emit cursor copy
__global__ __launch_bounds__(256) void k_scan_bc(int* __restrict__ offs,
                                                 const int* __restrict__ bsum,
                                                 int* __restrict__ cur2) {
    __shared__ int sv[SCAN_TPB];
    __shared__ int se[SCAN_TPB];
    int v = (threadIdx.x < NB) ? bsum[threadIdx.x] : 0;
    sv[threadIdx.x] = v;
    __syncthreads();
    for (int o = 1; o < SCAN_TPB; o <<= 1) {
        int t = (threadIdx.x >= o) ? sv[threadIdx.x - o] : 0;
        __syncthreads();
        sv[threadIdx.x] += t;
        __syncthreads();
    }
    se[threadIdx.x] = sv[threadIdx.x] - v;   // exclusive
    __syncthreads();
    int i = blockIdx.x * 256 + threadIdx.x;  // grid = NPAD/256 exactly
    int o = offs[i] + se[blockIdx.x >> 2];   // (i>>10) constant per block
    offs[i] = o;
    cur2[i] = o;                             // running cursor for k_fill
}

// ---- fill: scatter ONLY the 4-B edge index (6.4 MB, L2-resident -> lines merge);
//      block 0 also converts the edge-attr weight rows to fp16 (folded k_wcvt) ----
__global__ __launch_bounds__(256) void k_fill(const int* __restrict__ ei,
                                              int* __restrict__ cur2,
                                              int* __restrict__ elist,
                                              const float* __restrict__ lfw,
                                              const float* __restrict__ lsw,
                                              __half2* __restrict__ wtab) {
    if (blockIdx.x == 0) {
        for (int t = threadIdx.x; t < 320; t += 256) {
            int l   = t / 160;
            int mat = (t / 80) & 1;
            int k   = (t / 10) % 8;
            int j   = t % 10;
            const float* src = (mat ? lsw : lfw) + (size_t)l * KK * CC + (2*CC + k) * CC + 2*j;
            wtab[t] = __floats2half2_rn(src[0], src[1]);
        }
    }
    int e = blockIdx.x * 256 + threadIdx.x;
    if (e >= EE) return;
    int d = __builtin_nontemporal_load(ei + EE + e);
    int pos = atomicAdd(&cur2[d], 1);        // cur2 pre-initialized to offs
    elist[pos] = e;
}

// ---- gather: coalesced record build (sequential writes, permuted reads) ----
__global__ __launch_bounds__(256) void k_gath(const int* __restrict__ elist,
                                              const int* __restrict__ ei,
                                              const float* __restrict__ ea,
                                              unsigned int* __restrict__ rec) {
    int i = blockIdx.x * 256 + threadIdx.x;
    if (i >= EE) return;
    int e = elist[i];
    int s = ei[e];
    int d = ei[EE + e];
    const float4* eap = reinterpret_cast<const float4*>(ea + (size_t)e * DD);
    float4 a = eap[0], b = eap[1];
    H2U h01; h01.h = __floats2half2_rn(a.x, a.y);
    H2U h23; h23.h = __floats2half2_rn(a.z, a.w);
    H2U h45; h45.h = __floats2half2_rn(b.x, b.y);
    H2U h67; h67.h = __floats2half2_rn(b.z, b.w);
    uint4* dst = reinterpret_cast<uint4*>(rec + (size_t)i * RSTRIDE);
    dst[0] = make_uint4((unsigned int)s, (unsigned int)d, h01.u, h23.u);
    dst[1] = make_uint4(h45.u, h67.u, 0u, 0u);
}

// ---- helper: pack 2*CC floats -> 20 half2 words and store as 5 uint4 ----
__device__ __forceinline__ void store_h40(__half* dstp,
                                          const float* fx, const float* gx) {
    unsigned int w[20];
#pragma unroll
    for (int j = 0; j < 10; ++j) {
        H2U cv; cv.h = __floats2half2_rn(fx[2*j], fx[2*j+1]);
        w[j] = cv.u;
    }
#pragma unroll
    for (int j = 0; j < 10; ++j) {
        H2U cv; cv.h = __floats2half2_rn(gx[2*j], gx[2*j+1]);
        w[10 + j] = cv.u;
    }
    uint4* d4 = reinterpret_cast<uint4*>(dstp);
#pragma unroll
    for (int i = 0; i < 5; ++i)
        d4[i] = make_uint4(w[4*i], w[4*i+1], w[4*i+2], w[4*i+3]);
}

// ---------------- per-node precompute (both tables fp16) ----------------
__global__ __launch_bounds__(256) void k_pre0(
    const float* __restrict__ x,
    const float* __restrict__ wf, const float* __restrict__ bf,
    const float* __restrict__ wsm, const float* __restrict__ bs,
    __half* __restrict__ P0h, __half* __restrict__ PXh, float* __restrict__ y)
{
    int n = blockIdx.x * 256 + threadIdx.x;
    if (n >= NN) return;
    float xn[CC];
    const float4* xp = reinterpret_cast<const float4*>(x + (size_t)n * CC);
    float4* yp = reinterpret_cast<float4*>(y + (size_t)n * CC);
#pragma unroll
    for (int q = 0; q < 5; ++q) {
        float4 t = xp[q];
        yp[q] = t;
        xn[4*q+0] = t.x; xn[4*q+1] = t.y; xn[4*q+2] = t.z; xn[4*q+3] = t.w;
    }
    float f0[CC], g0[CC], fx[CC], gx[CC];
#pragma unroll
    for (int c = 0; c < CC; ++c) { f0[c] = bf[c]; g0[c] = bs[c]; fx[c] = 0.f; gx[c] = 0.f; }
#pragma unroll
    for (int k = 0; k < CC; ++k) {
        float zk = xn[k];
#pragma unroll
        for (int c = 0; c < CC; ++c) {
            f0[c] = fmaf(zk, wf[k*CC + c], f0[c]);
            g0[c] = fmaf(zk, wsm[k*CC + c], g0[c]);
            fx[c] = fmaf(zk, wf[(CC+k)*CC + c], fx[c]);
            gx[c] = fmaf(zk, wsm[(CC+k)*CC + c], gx[c]);
        }
    }
    store_h40(P0h + (size_t)n * 2*CC, f0, g0);
    store_h40(PXh + (size_t)n * 2*CC, fx, gx);
}

// ---------------- BN(prev layer) + tanh in place, then P0h/PXh for next layer
__global__ __launch_bounds__(256) void k_bnpre(
    float* __restrict__ y, const float* __restrict__ sums,
    const float* __restrict__ gam, const float* __restrict__ bet,
    const float* __restrict__ wf, const float* __restrict__ bf,
    const float* __restrict__ wsm, const float* __restrict__ bs,
    __half* __restrict__ P0h, __half* __restrict__ PXh)
{
    int n = blockIdx.x * 256 + threadIdx.x;
    if (n >= NN) return;
    const float inv = 1.0f / (float)NN;
    float4* yp = reinterpret_cast<float4*>(y + (size_t)n * CC);
    float xn[CC];
#pragma unroll
    for (int q = 0; q < 5; ++q) {
        float4 t = yp[q];
        xn[4*q+0] = t.x; xn[4*q+1] = t.y; xn[4*q+2] = t.z; xn[4*q+3] = t.w;
    }
#pragma unroll
    for (int c = 0; c < CC; ++c) {
        float mean = sums[c] * inv;
        float var  = sums[CC + c] * inv - mean * mean;
        float scale = gam[c] * rsqrtf(var + EPSV);
        float shift = bet[c] - mean * scale;
        xn[c] = tanhf(fmaf(xn[c], scale, shift));
    }
#pragma unroll
    for (int q = 0; q < 5; ++q)
        yp[q] = make_float4(xn[4*q+0], xn[4*q+1], xn[4*q+2], xn[4*q+3]);

    float f0[CC], g0[CC], fx[CC], gx[CC];
#pragma unroll
    for (int c = 0; c < CC; ++c) { f0[c] = bf[c]; g0[c] = bs[c]; fx[c] = 0.f; gx[c] = 0.f; }
#pragma unroll
    for (int k = 0; k < CC; ++k) {
        float zk = xn[k];
#pragma unroll
        for (int c = 0; c < CC; ++c) {
            f0[c] = fmaf(zk, wf[k*CC + c], f0[c]);
            g0[c] = fmaf(zk, wsm[k*CC + c], g0[c]);
            fx[c] = fmaf(zk, wf[(CC+k)*CC + c], fx[c]);
            gx[c] = fmaf(zk, wsm[(CC+k)*CC + c], gx[c]);
        }
    }
    store_h40(P0h + (size_t)n * 2*CC, f0, g0);
    store_h40(PXh + (size_t)n * 2*CC, fx, gx);
}

// ---------------- k_msg helpers ----------------
__device__ __forceinline__ void rec_read(const unsigned int* __restrict__ rec, int i,
                                         int& s, int& d, __half2* ebc) {
    const uint4* rp = reinterpret_cast<const uint4*>(rec + (size_t)i * RSTRIDE);
    uint4 r0 = rp[0], r1 = rp[1];
    s = (int)r0.x;
    d = (int)r0.y;
    H2U a; a.u = r0.z; ebc[0] = __low2half2(a.h); ebc[1] = __high2half2(a.h);
    H2U b; b.u = r0.w; ebc[2] = __low2half2(b.h); ebc[3] = __high2half2(b.h);
    H2U c; c.u = r1.x; ebc[4] = __low2half2(c.h); ebc[5] = __high2half2(c.h);
    H2U e; e.u = r1.y; ebc[6] = __low2half2(e.h); ebc[7] = __high2half2(e.h);
}

__device__ __forceinline__ void load_p0(const __half* __restrict__ P0h, int d,
                                        unsigned int* p0c) {
    const uint4* p = reinterpret_cast<const uint4*>(P0h + (size_t)d * 2*CC);
    uint4 z0 = p[0], z1 = p[1], z2 = p[2], z3 = p[3], z4 = p[4];
    p0c[0]=z0.x;  p0c[1]=z0.y;  p0c[2]=z0.z;  p0c[3]=z0.w;
    p0c[4]=z1.x;  p0c[5]=z1.y;  p0c[6]=z1.z;  p0c[7]=z1.w;
    p0c[8]=z2.x;  p0c[9]=z2.y;  p0c[10]=z2.z; p0c[11]=z2.w;
    p0c[12]=z3.x; p0c[13]=z3.y; p0c[14]=z3.z; p0c[15]=z3.w;
    p0c[16]=z4.x; p0c[17]=z4.y; p0c[18]=z4.z; p0c[19]=z4.w;
}

__device__ __forceinline__ void msg_compute(const unsigned int* p0c,
    const __half* __restrict__ PXh, int s, const __half2* ebc,
    const __half2* __restrict__ whf, const __half2* __restrict__ whs,
    float* m)
{
    const uint4* pxp = reinterpret_cast<const uint4*>(PXh + (size_t)s * 2*CC);
    uint4 x0 = pxp[0], x1 = pxp[1], x2 = pxp[2], x3 = pxp[3], x4 = pxp[4];
    unsigned int xw[20] = {x0.x, x0.y, x0.z, x0.w, x1.x, x1.y, x1.z, x1.w,
                           x2.x, x2.y, x2.z, x2.w, x3.x, x3.y, x3.z, x3.w,
                           x4.x, x4.y, x4.z, x4.w};
    __half2 fh[10], gh[10];
#pragma unroll
    for (int j = 0; j < 10; ++j) {
        H2U a; a.u = xw[j];
        H2U b; b.u = p0c[j];
        fh[j] = __hadd2(a.h, b.h);
    }
#pragma unroll
    for (int j = 0; j < 10; ++j) {
        H2U a; a.u = xw[10 + j];
        H2U b; b.u = p0c[10 + j];
        gh[j] = __hadd2(a.h, b.h);
    }
#pragma unroll
    for (int k = 0; k < 8; ++k) {
        __half2 bc = ebc[k];
#pragma unroll
        for (int j = 0; j < 10; ++j) {
            fh[j] = __hfma2(bc, whf[k*10 + j], fh[j]);
            gh[j] = __hfma2(bc, whs[k*10 + j], gh[j]);
        }
    }
#pragma unroll
    for (int j = 0; j < 10; ++j) {
        float2 ff = __half22float2(fh[j]);
        float2 gg = __half22float2(gh[j]);
        float sg0 = 1.0f / (1.0f + __expf(-ff.x));
        float sg1 = 1.0f / (1.0f + __expf(-ff.y));
        float sp0 = fmaxf(gg.x, 0.0f) + __logf(1.0f + __expf(-fabsf(gg.x)));
        float sp1 = fmaxf(gg.y, 0.0f) + __logf(1.0f + __expf(-fabsf(gg.y)));
        m[2*j]   = sg0 * sp0;
        m[2*j+1] = sg1 * sp1;
    }
}

__device__ __forceinline__ void commit(float* __restrict__ y, int d,
                                       const float* acc, bool complete) {
    float* yp = y + (size_t)d * CC;
    if (complete) {
        float4* y4 = reinterpret_cast<float4*>(yp);
#pragma unroll
        for (int q = 0; q < 5; ++q) {
            float4 t = y4[q];
            t.x += acc[4*q+0]; t.y += acc[4*q+1];
            t.z += acc[4*q+2]; t.w += acc[4*q+3];
            y4[q] = t;
        }
    } else {
#pragma unroll
        for (int c = 0; c < CC; ++c) atomicAdd(yp + c, acc[c]);
    }
}

// ---------------- fused edge kernel: EPT sorted edges/thread, wave seg-reduce ----------------
__global__ __launch_bounds__(256) void k_msg(
    const unsigned int* __restrict__ rec, const int* __restrict__ offs,
    const __half* __restrict__ P0h, const __half* __restrict__ PXh,
    const __half2* __restrict__ whf, const __half2* __restrict__ whs,
    float* __restrict__ y)
{
    int t = blockIdx.x * 256 + threadIdx.x;
    int i0 = t * EPT;
    if (i0 >= EE) return;               // whole-wave uniform exit (EE/EPT % 64 == 0)
    int lane = threadIdx.x & 63;
    int W = i0 & ~(64*EPT - 1);         // wave's first sorted-edge index

    unsigned int p0c[20];
    __half2 ebc[8];
    float trail[CC], lead[CC], m[CC];
    int trail_d, lead_d = -1, cur_d;

    {
        int s0, d0;
        rec_read(rec, i0, s0, d0, ebc);
        load_p0(P0h, d0, p0c); cur_d = d0;
        msg_compute(p0c, PXh, s0, ebc, whf, whs, trail);
        trail_d = d0;
    }
#pragma unroll
    for (int j = 1; j < EPT; ++j) {
        int sj, dj;
        rec_read(rec, i0 + j, sj, dj, ebc);
        if (dj != cur_d) { load_p0(P0h, dj, p0c); cur_d = dj; }
        msg_compute(p0c, PXh, sj, ebc, whf, whs, m);
        if (dj == trail_d) {
#pragma unroll
            for (int c = 0; c < CC; ++c) trail[c] += m[c];
        } else {
            if (lead_d < 0) {
#pragma unroll
                for (int c = 0; c < CC; ++c) lead[c] = trail[c];
                lead_d = trail_d;
            } else {
                commit(y, trail_d, trail, true);   // run fully inside thread
            }
#pragma unroll
            for (int c = 0; c < CC; ++c) trail[c] = m[c];
            trail_d = dj;
        }
    }

    // segmented inclusive scan of trail across lanes (d monotone -> simple pred)
    float mk[6];
#pragma unroll
    for (int k = 0; k < 6; ++k) {
        int off = 1 << k;
        int dfrom = __shfl_up(trail_d, off);
        mk[k] = (lane >= off && dfrom == trail_d) ? 1.0f : 0.0f;
    }
#pragma unroll
    for (int k = 0; k < 6; ++k) {
        int off = 1 << k;
#pragma unroll
        for (int c = 0; c < CC; ++c) {
            float tt = __shfl_up(trail[c], off);
            trail[c] = fmaf(tt, mk[k], trail[c]);
        }
    }
    int dt_next = __shfl_down(trail_d, 1);
    int ld_next = __shfl_down(lead_d, 1);
    int d_prev = __shfl_up(trail_d, 1);
    float gate = (lane > 0 && d_prev == lead_d) ? 1.0f : 0.0f;
#pragma unroll
    for (int c = 0; c < CC; ++c) {
        float tt = __shfl_up(trail[c], 1);
        lead[c] = fmaf(tt, gate, lead[c]);
    }

    bool tail = (lane == 63) || (dt_next != trail_d && ld_next != trail_d);
    if (tail) {
        int o0 = offs[trail_d], o1 = offs[trail_d + 1];
        bool complete = (o0 >= W) && (o1 == i0 + EPT);
        commit(y, trail_d, trail, complete);
    }
    if (lead_d >= 0) {
        int o0 = offs[lead_d];
        commit(y, lead_d, lead, o0 >= W);   // run ends mid-thread -> within wave
    }
}

// ---------------- BN stats: grid-stride, block-level reduction ----------------
#define STAT_BLOCKS 128
__global__ __launch_bounds__(256) void k_bnstats(const float* __restrict__ y,
                                                 float* __restrict__ sums)
{
    __shared__ float ls[4][2 * CC];
    float s0[CC], s1[CC];
#pragma unroll
    for (int c = 0; c < CC; ++c) { s0[c] = 0.0f; s1[c] = 0.0f; }
    for (int n = blockIdx.x * 256 + threadIdx.x; n < NN; n += STAT_BLOCKS * 256) {
        const float4* p = reinterpret_cast<const float4*>(y + (size_t)n * CC);
#pragma unroll
        for (int q = 0; q < 5; ++q) {
            float4 t = p[q];
            s0[4*q+0] += t.x; s1[4*q+0] += t.x * t.x;
            s0[4*q+1] += t.y; s1[4*q+1] += t.y * t.y;
            s0[4*q+2] += t.z; s1[4*q+2] += t.z * t.z;
            s0[4*q+3] += t.w; s1[4*q+3] += t.w * t.w;
        }
    }
    int lane = threadIdx.x & 63;
    int wave = threadIdx.x >> 6;
#pragma unroll
    for (int c = 0; c < CC; ++c) {
        float a = s0[c], b = s1[c];
        for (int o = 32; o > 0; o >>= 1) {
            a += __shfl_down(a, o);
            b += __shfl_down(b, o);
        }
        if (lane == 0) { ls[wave][c] = a; ls[wave][CC + c] = b; }
    }
    __syncthreads();
    if (threadIdx.x < 2 * CC) {
        float tot = ls[0][threadIdx.x] + ls[1][threadIdx.x] +
                    ls[2][threadIdx.x] + ls[3][threadIdx.x];
        atomicAdd(&sums[threadIdx.x], tot);
    }
}

// ---------------- final: BN + tanh + pool via wave segmented scan ----------------
__global__ __launch_bounds__(256) void k_bnpool(
    const float* __restrict__ y, const float* __restrict__ sums,
    const float* __restrict__ gam, const float* __restrict__ bet,
    const int* __restrict__ batch, float* __restrict__ pooled)
{
    int n = blockIdx.x * 256 + threadIdx.x;
    int nc = n < NN ? n : NN - 1;
    bool valid = n < NN;
    int g = batch[nc];                 // pad lanes: g of last node, v = 0
    const float inv = 1.0f / (float)NN;
    float v[CC];
    const float4* p = reinterpret_cast<const float4*>(y + (size_t)nc * CC);
#pragma unroll
    for (int q = 0; q < 5; ++q) {
        float4 t = p[q];
        v[4*q+0] = t.x; v[4*q+1] = t.y; v[4*q+2] = t.z; v[4*q+3] = t.w;
    }
#pragma unroll
    for (int c = 0; c < CC; ++c) {
        float mean = sums[c] * inv;
        float var  = sums[CC + c] * inv - mean * mean;
        float scale = gam[c] * rsqrtf(var + EPSV);
        float shift = bet[c] - mean * scale;
        v[c] = tanhf(fmaf(v[c], scale, shift));
        if (!valid) v[c] = 0.0f;
    }
    // segmented inclusive scan across the wave keyed by g (batch sorted)
    int lane = threadIdx.x & 63;
    float mk[6];
#pragma unroll
    for (int k = 0; k < 6; ++k) {
        int off = 1 << k;
        int gfrom = __shfl_up(g, off);
        mk[k] = (lane >= off && gfrom == g) ? 1.0f : 0.0f;
    }
#pragma unroll
    for (int k = 0; k < 6; ++k) {
        int off = 1 << k;
#pragma unroll
        for (int c = 0; c < CC; ++c) {
            float tt = __shfl_up(v[c], off);
            v[c] = fmaf(tt, mk[k], v[c]);
        }
    }
    int g_next = __shfl_down(g, 1);
    bool tail = (lane == 63) || (g_next != g);
    if (tail) {
#pragma unroll
        for (int c = 0; c < CC; ++c)
            atomicAdd(&pooled[(size_t)g * CC + c], v[c]);
    }
}

// ---------------- final MLP ----------------
__global__ __launch_bounds__(256) void k_mlp(const float* __restrict__ pooled,
    const float* __restrict__ w1, const float* __restrict__ b1,
    const float* __restrict__ w2, const float* __restrict__ b2,
    const float* __restrict__ w3, const float* __restrict__ b3,
    float* __restrict__ out)
{
    int gi = blockIdx.x * 256 + threadIdx.x;
    if (gi >= GG) return;

    float p[CC];
    const float4* pp = reinterpret_cast<const float4*>(pooled + (size_t)gi * CC);
#pragma unroll
    for (int q = 0; q < 5; ++q) {
        float4 t = pp[q];
        p[4*q+0] = t.x; p[4*q+1] = t.y; p[4*q+2] = t.z; p[4*q+3] = t.w;
    }
    float h1[32];
#pragma unroll
    for (int j = 0; j < 32; ++j) h1[j] = b1[j];
#pragma unroll
    for (int c = 0; c < CC; ++c) {
        float pc = p[c];
#pragma unroll
        for (int j = 0; j < 32; ++j) h1[j] = fmaf(pc, w1[c*32 + j], h1[j]);
    }
#pragma unroll
    for (int j = 0; j < 32; ++j) h1[j] = tanhf(h1[j]);
    float h2[8];
#pragma unroll
    for (int j = 0; j < 8; ++j) h2[j] = b2[j];
#pragma unroll
    for (int c = 0; c < 32; ++c) {
        float hc = h1[c];
#pragma unroll
        for (int j = 0; j < 8; ++j) h2[j] = fmaf(hc, w2[c*8 + j], h2[j]);
    }
    float o = b3[0];
#pragma unroll
    for (int j = 0; j < 8; ++j) o = fmaf(tanhf(h2[j]), w3[j], o);
    out[gi] = o;
}

extern "C" void kernel_launch(void* const* d_in, const int* in_sizes, int n_in,
                              void* d_out, int out_size, void* d_ws, size_t ws_size,
                              hipStream_t stream) {
    const float* x   = (const float*)d_in[0];
    const int*   ei  = (const int*)d_in[1];
    const float* ea  = (const float*)d_in[2];
    const int*   bat = (const int*)d_in[3];
    const float* lfw = (const float*)d_in[4];
    const float* lfb = (const float*)d_in[5];
    const float* lsw = (const float*)d_in[6];
    const float* lsb = (const float*)d_in[7];
    const float* bng = (const float*)d_in[8];
    const float* bnb = (const float*)d_in[9];
    const float* w1  = (const float*)d_in[10];
    const float* b1  = (const float*)d_in[11];
    const float* w2  = (const float*)d_in[12];
    const float* b2  = (const float*)d_in[13];
    const float* w3  = (const float*)d_in[14];
    const float* b3  = (const float*)d_in[15];
    float* out = (float*)d_out;

    char* ws = (char*)d_ws;
    float*        y      = (float*)ws;                          // NN*CC f    (8 MB)
    __half*       P0h    = (__half*)(y + (size_t)NN * CC);      // NN*2CC h   (8 MB)
    __half*       PXh    = P0h + (size_t)NN * 2 * CC;           // NN*2CC h   (8 MB)
    unsigned int* rec    = (unsigned int*)(PXh + (size_t)NN * 2 * CC); // EE*8 u (51.2 MB)
    int*          elist  = (int*)(rec + (size_t)EE * RSTRIDE);  // EE ints    (6.4 MB)
    int*          offs   = elist + EE;                          // NPAD
    int*          cur2   = offs + NPAD;                         // NPAD (written by scan_bc)
    __half2*      wtab   = (__half2*)(cur2 + NPAD);             // 320 half2 = 640 B
    int*          bsum   = (int*)(wtab + 320);                  // 256
    // zeroed region starts here:
    int*          cnt    = bsum + 256;                          // NN
    float*        sums   = (float*)(cnt + NN);                  // 2 layers * 2*CC
    float*        pooled = sums + 2 * 2 * CC;                   // GG*CC

    size_t zbytes = ((size_t)NN + 2*2*CC + (size_t)GG*CC) * sizeof(int);
    hipMemsetAsync(cnt, 0, zbytes, stream);

    // ---- CSR build + index scatter + coalesced record build ----
    k_hist<<<(EE/4 + 255) / 256, 256, 0, stream>>>(ei, cnt);
    k_scan_a<<<NB, SCAN_TPB, 0, stream>>>(cnt, offs, bsum);
    k_scan_bc<<<NPAD / 256, 256, 0, stream>>>(offs, bsum, cur2);
    k_fill<<<(EE + 255) / 256, 256, 0, stream>>>(ei, cur2, elist, lfw, lsw, wtab);
    k_gath<<<(EE + 255) / 256, 256, 0, stream>>>(elist, ei, ea, rec);

    const int nblocks = (NN + 255) / 256;
    const int mblocks = (EE / EPT + 255) / 256;   // 782

    // layer 0
    k_pre0<<<nblocks, 256, 0, stream>>>(x, lfw, lfb, lsw, lsb, P0h, PXh, y);
    k_msg<<<mblocks, 256, 0, stream>>>(rec, offs, P0h, PXh,
                                       wtab, wtab + 80, y);
    k_bnstats<<<STAT_BLOCKS, 256, 0, stream>>>(y, sums);
    // BN(l0)+tanh in place, precompute P0h/PXh for layer 1
    k_bnpre<<<nblocks, 256, 0, stream>>>(y, sums, bng, bnb,
        lfw + (size_t)KK*CC, lfb + CC, lsw + (size_t)KK*CC, lsb + CC, P0h, PXh);
    // layer 1
    k_msg<<<mblocks, 256, 0, stream>>>(rec, offs, P0h, PXh,
        wtab + 160, wtab + 240, y);
    k_bnstats<<<STAT_BLOCKS, 256, 0, stream>>>(y, sums + 2*CC);
    // BN(l1)+tanh+pool
    k_bnpool<<<nblocks, 256, 0, stream>>>(y, sums + 2*CC, bng + CC, bnb + CC,
                                          bat, pooled);
    k_mlp<<<(GG + 255) / 256, 256, 0, stream>>>(pooled, w1, b1, w2, b2, w3, b3, out);
}

// Round 17
// 436.341 us; speedup vs baseline: 1.3375x; 1.3375x over previous
//
#include <hip/hip_runtime.h>
#include <hip/hip_fp16.h>
#include <math.h>

#define NN 100000
#define EE 1600000
#define CC 20
#define DD 8
#define GG 1024
#define LL 2
#define KK (2*CC+DD)   // 48
#define EPSV 1e-5f

#define SCAN_TPB 256
#define SCAN_ELEMS 4
#define NB 98                      // ceil(NN / 1024)
#define NPAD (NB * SCAN_TPB * SCAN_ELEMS)  // 100352
#define RSTRIDE 8                  // record = 8 dwords = 32 B {s,d, 8×half, pad}
#define RBLK 6250                  // ceil(EE/256) edge blocks in fused k_rec
#define NBLK 391                   // ceil(NN/256) node blocks

union H2U { __half2 h; unsigned int u; };

// native clang vector types for nontemporal builtins (HIP float4/int4 are rejected)
typedef float nf4 __attribute__((ext_vector_type(4)));
typedef int   ni4 __attribute__((ext_vector_type(4)));

__device__ __forceinline__ float4 ntload_f4(const float* p) {
    nf4 v = __builtin_nontemporal_load(reinterpret_cast<const nf4*>(p));
    return make_float4(v.x, v.y, v.z, v.w);
}

// ---- helper: pack 2*CC floats -> 20 half2 words and store as 5 uint4 ----
__device__ __forceinline__ void store_h40(__half* dstp,
                                          const float* fx, const float* gx) {
    unsigned int w[20];
#pragma unroll
    for (int j = 0; j < 10; ++j) {
        H2U cv; cv.h = __floats2half2_rn(fx[2*j], fx[2*j+1]);
        w[j] = cv.u;
    }
#pragma unroll
    for (int j = 0; j < 10; ++j) {
        H2U cv; cv.h = __floats2half2_rn(gx[2*j], gx[2*j+1]);
        w[10 + j] = cv.u;
    }
    uint4* d4 = reinterpret_cast<uint4*>(dstp);
#pragma unroll
    for (int i = 0; i < 5; ++i)
        d4[i] = make_uint4(w[4*i], w[4*i+1], w[4*i+2], w[4*i+3]);
}

// ---------------- CSR build (block 0 also builds fp16 weight table) ----------------
__global__ __launch_bounds__(256) void k_hist(const int* __restrict__ ei,
                                              int* __restrict__ cnt,
                                              const float* __restrict__ lfw,
                                              const float* __restrict__ lsw,
                                              __half2* __restrict__ wtab) {
    if (blockIdx.x == 0) {
        for (int t = threadIdx.x; t < 320; t += 256) {
            int l   = t / 160;
            int mat = (t / 80) & 1;
            int k   = (t / 10) % 8;
            int j   = t % 10;
            const float* src = (mat ? lsw : lfw) + (size_t)l * KK * CC + (2*CC + k) * CC + 2*j;
            wtab[t] = __floats2half2_rn(src[0], src[1]);
        }
    }
    int t = blockIdx.x * 256 + threadIdx.x;
    if (t * 4 >= EE) return;
    ni4 d4 = __builtin_nontemporal_load(reinterpret_cast<const ni4*>(ei + EE) + t);
    atomicAdd(&cnt[d4.x], 1);
    atomicAdd(&cnt[d4.y], 1);
    atomicAdd(&cnt[d4.z], 1);
    atomicAdd(&cnt[d4.w], 1);
}

__global__ __launch_bounds__(SCAN_TPB) void k_scan_a(const int* __restrict__ cnt,
                                                     int* __restrict__ offs,
                                                     int* __restrict__ bsum) {
    __shared__ int sdata[SCAN_TPB];
    int base = blockIdx.x * (SCAN_TPB * SCAN_ELEMS) + threadIdx.x * SCAN_ELEMS;
    int v[SCAN_ELEMS];
    int tot = 0;
#pragma unroll
    for (int i = 0; i < SCAN_ELEMS; ++i) {
        int idx = base + i;
        v[i] = (idx < NN) ? cnt[idx] : 0;
        tot += v[i];
    }
    sdata[threadIdx.x] = tot;
    __syncthreads();
    for (int o = 1; o < SCAN_TPB; o <<= 1) {
        int t = (threadIdx.x >= o) ? sdata[threadIdx.x - o] : 0;
        __syncthreads();
        sdata[threadIdx.x] += t;
        __syncthreads();
    }
    int run = sdata[threadIdx.x] - tot;  // exclusive prefix of this thread
#pragma unroll
    for (int i = 0; i < SCAN_ELEMS; ++i) {
        offs[base + i] = run;
        run += v[i];
    }
    if (threadIdx.x == SCAN_TPB - 1) bsum[blockIdx.x] = sdata[threadIdx.x];
}

// scan of bsum (redundant per block) + add to offs; also emit cursor copy
__global__ __launch_bounds__(256) void k_scan_bc(int* __restrict__ offs,
                                                 const int* __restrict__ bsum,
                                                 int* __restrict__ cur2) {
    __shared__ int sv[SCAN_TPB];
    __shared__ int se[SCAN_TPB];
    int v = (threadIdx.x < NB) ? bsum[threadIdx.x] : 0;
    sv[threadIdx.x] = v;
    __syncthreads();
    for (int o = 1; o < SCAN_TPB; o <<= 1) {
        int t = (threadIdx.x >= o) ? sv[threadIdx.x - o] : 0;
        __syncthreads();
        sv[threadIdx.x] += t;
        __syncthreads();
    }
    se[threadIdx.x] = sv[threadIdx.x] - v;   // exclusive
    __syncthreads();
    int i = blockIdx.x * 256 + threadIdx.x;  // grid = NPAD/256 exactly
    int o = offs[i] + se[blockIdx.x >> 2];   // (i>>10) constant per block
    offs[i] = o;
    cur2[i] = o;                             // running cursor for k_rec
}

// ---- fused: record scatter (blocks < RBLK) + per-node precompute (blocks >= RBLK) ----
// record: one 32-B fp16 record per edge, regular stores (scatter = line RMW; pay once)
// pre0: P0h = [bf + x@Wf[0:20] | bs + x@Ws[0:20]], PXh = [x@Wf[20:40] | x@Ws[20:40]],
//       y := x  (dense work hides under the scatter's latency-bound phase)
__global__ __launch_bounds__(256) void k_rec(const int* __restrict__ ei,
                                             const float* __restrict__ ea,
                                             int* __restrict__ cur2,
                                             unsigned int* __restrict__ rec,
                                             const float* __restrict__ x,
                                             const float* __restrict__ wf,
                                             const float* __restrict__ bf,
                                             const float* __restrict__ wsm,
                                             const float* __restrict__ bs,
                                             __half* __restrict__ P0h,
                                             __half* __restrict__ PXh,
                                             float* __restrict__ y) {
    if (blockIdx.x >= RBLK) {
        // ---- pre0 part ----
        int n = (blockIdx.x - RBLK) * 256 + threadIdx.x;
        if (n >= NN) return;
        float xn[CC];
        const float4* xp = reinterpret_cast<const float4*>(x + (size_t)n * CC);
        float4* yp = reinterpret_cast<float4*>(y + (size_t)n * CC);
#pragma unroll
        for (int q = 0; q < 5; ++q) {
            float4 t = xp[q];
            yp[q] = t;
            xn[4*q+0] = t.x; xn[4*q+1] = t.y; xn[4*q+2] = t.z; xn[4*q+3] = t.w;
        }
        float f0[CC], g0[CC], fx[CC], gx[CC];
#pragma unroll
        for (int c = 0; c < CC; ++c) { f0[c] = bf[c]; g0[c] = bs[c]; fx[c] = 0.f; gx[c] = 0.f; }
#pragma unroll
        for (int k = 0; k < CC; ++k) {
            float zk = xn[k];
#pragma unroll
            for (int c = 0; c < CC; ++c) {
                f0[c] = fmaf(zk, wf[k*CC + c], f0[c]);
                g0[c] = fmaf(zk, wsm[k*CC + c], g0[c]);
                fx[c] = fmaf(zk, wf[(CC+k)*CC + c], fx[c]);
                gx[c] = fmaf(zk, wsm[(CC+k)*CC + c], gx[c]);
            }
        }
        store_h40(P0h + (size_t)n * 2*CC, f0, g0);
        store_h40(PXh + (size_t)n * 2*CC, fx, gx);
        return;
    }
    // ---- record scatter part ----
    int e = blockIdx.x * 256 + threadIdx.x;
    if (e >= EE) return;
    int s = __builtin_nontemporal_load(ei + e);
    int d = __builtin_nontemporal_load(ei + EE + e);
    int pos = atomicAdd(&cur2[d], 1);        // cur2 pre-initialized to offs
    float4 a = ntload_f4(ea + (size_t)e * DD);
    float4 b = ntload_f4(ea + (size_t)e * DD + 4);
    H2U h01; h01.h = __floats2half2_rn(a.x, a.y);
    H2U h23; h23.h = __floats2half2_rn(a.z, a.w);
    H2U h45; h45.h = __floats2half2_rn(b.x, b.y);
    H2U h67; h67.h = __floats2half2_rn(b.z, b.w);
    uint4* dst = reinterpret_cast<uint4*>(rec + (size_t)pos * RSTRIDE);
    dst[0] = make_uint4((unsigned int)s, (unsigned int)d, h01.u, h23.u);
    dst[1] = make_uint4(h45.u, h67.u, 0u, 0u);
}

// ---------------- BN(prev layer) + tanh in place, then P0h/PXh for next layer
__global__ __launch_bounds__(256) void k_bnpre(
    float* __restrict__ y, const float* __restrict__ sums,
    const float* __restrict__ gam, const float* __restrict__ bet,
    const float* __restrict__ wf, const float* __restrict__ bf,
    const float* __restrict__ wsm, const float* __restrict__ bs,
    __half* __restrict__ P0h, __half* __restrict__ PXh)
{
    int n = blockIdx.x * 256 + threadIdx.x;
    if (n >= NN) return;
    const float inv = 1.0f / (float)NN;
    float4* yp = reinterpret_cast<float4*>(y + (size_t)n * CC);
    float xn[CC];
#pragma unroll
    for (int q = 0; q < 5; ++q) {
        float4 t = yp[q];
        xn[4*q+0] = t.x; xn[4*q+1] = t.y; xn[4*q+2] = t.z; xn[4*q+3] = t.w;
    }
#pragma unroll
    for (int c = 0; c < CC; ++c) {
        float mean = sums[c] * inv;
        float var  = sums[CC + c] * inv - mean * mean;
        float scale = gam[c] * rsqrtf(var + EPSV);
        float shift = bet[c] - mean * scale;
        xn[c] = tanhf(fmaf(xn[c], scale, shift));
    }
#pragma unroll
    for (int q = 0; q < 5; ++q)
        yp[q] = make_float4(xn[4*q+0], xn[4*q+1], xn[4*q+2], xn[4*q+3]);

    float f0[CC], g0[CC], fx[CC], gx[CC];
#pragma unroll
    for (int c = 0; c < CC; ++c) { f0[c] = bf[c]; g0[c] = bs[c]; fx[c] = 0.f; gx[c] = 0.f; }
#pragma unroll
    for (int k = 0; k < CC; ++k) {
        float zk = xn[k];
#pragma unroll
        for (int c = 0; c < CC; ++c) {
            f0[c] = fmaf(zk, wf[k*CC + c], f0[c]);
            g0[c] = fmaf(zk, wsm[k*CC + c], g0[c]);
            fx[c] = fmaf(zk, wf[(CC+k)*CC + c], fx[c]);
            gx[c] = fmaf(zk, wsm[(CC+k)*CC + c], gx[c]);
        }
    }
    store_h40(P0h + (size_t)n * 2*CC, f0, g0);
    store_h40(PXh + (size_t)n * 2*CC, fx, gx);
}

// ---------------- edge message: packed fp16 GEMM ----------------
__device__ __forceinline__ void edge_msg(int i, int& d_out,
    const unsigned int* __restrict__ rec, const __half* __restrict__ P0h,
    const __half* __restrict__ PXh,
    const __half2* __restrict__ whf, const __half2* __restrict__ whs,
    float* m)
{
    const uint4* rp = reinterpret_cast<const uint4*>(rec + (size_t)i * RSTRIDE);
    uint4 r0 = rp[0], r1 = rp[1];
    int s = (int)r0.x;
    int d = (int)r0.y;
    d_out = d;
    __half2 ebc[8];
    {
        H2U a; a.u = r0.z;
        ebc[0] = __low2half2(a.h);  ebc[1] = __high2half2(a.h);
        H2U b; b.u = r0.w;
        ebc[2] = __low2half2(b.h);  ebc[3] = __high2half2(b.h);
        H2U c; c.u = r1.x;
        ebc[4] = __low2half2(c.h);  ebc[5] = __high2half2(c.h);
        H2U e; e.u = r1.y;
        ebc[6] = __low2half2(e.h);  ebc[7] = __high2half2(e.h);
    }

    const uint4* pxp = reinterpret_cast<const uint4*>(PXh + (size_t)s * 2*CC);
    const uint4* p0p = reinterpret_cast<const uint4*>(P0h + (size_t)d * 2*CC);
    uint4 x0 = pxp[0], x1 = pxp[1], x2 = pxp[2], x3 = pxp[3], x4 = pxp[4];
    uint4 z0 = p0p[0], z1 = p0p[1], z2 = p0p[2], z3 = p0p[3], z4 = p0p[4];
    unsigned int xw[20] = {x0.x, x0.y, x0.z, x0.w, x1.x, x1.y, x1.z, x1.w,
                           x2.x, x2.y, x2.z, x2.w, x3.x, x3.y, x3.z, x3.w,
                           x4.x, x4.y, x4.z, x4.w};
    unsigned int zw[20] = {z0.x, z0.y, z0.z, z0.w, z1.x, z1.y, z1.z, z1.w,
                           z2.x, z2.y, z2.z, z2.w, z3.x, z3.y, z3.z, z3.w,
                           z4.x, z4.y, z4.z, z4.w};
    __half2 fh[10], gh[10];
#pragma unroll
    for (int j = 0; j < 10; ++j) {
        H2U a; a.u = xw[j];
        H2U b; b.u = zw[j];
        fh[j] = __hadd2(a.h, b.h);
    }
#pragma unroll
    for (int j = 0; j < 10; ++j) {
        H2U a; a.u = xw[10 + j];
        H2U b; b.u = zw[10 + j];
        gh[j] = __hadd2(a.h, b.h);
    }
    // edge-attr GEMM in packed fp16: rows 2CC..KK-1
#pragma unroll
    for (int k = 0; k < 8; ++k) {
        __half2 bc = ebc[k];
#pragma unroll
        for (int j = 0; j < 10; ++j) {
            fh[j] = __hfma2(bc, whf[k*10 + j], fh[j]);
            gh[j] = __hfma2(bc, whs[k*10 + j], gh[j]);
        }
    }
#pragma unroll
    for (int j = 0; j < 10; ++j) {
        float2 ff = __half22float2(fh[j]);
        float2 gg = __half22float2(gh[j]);
        float sg0 = 1.0f / (1.0f + __expf(-ff.x));
        float sg1 = 1.0f / (1.0f + __expf(-ff.y));
        float sp0 = fmaxf(gg.x, 0.0f) + __logf(1.0f + __expf(-fabsf(gg.x)));
        float sp1 = fmaxf(gg.y, 0.0f) + __logf(1.0f + __expf(-fabsf(gg.y)));
        m[2*j]   = sg0 * sp0;
        m[2*j+1] = sg1 * sp1;
    }
}

__device__ __forceinline__ void commit(float* __restrict__ y, int d,
                                       const float* acc, bool complete) {
    float* yp = y + (size_t)d * CC;
    if (complete) {
        float4* y4 = reinterpret_cast<float4*>(yp);
#pragma unroll
        for (int q = 0; q < 5; ++q) {
            float4 t = y4[q];
            t.x += acc[4*q+0]; t.y += acc[4*q+1];
            t.z += acc[4*q+2]; t.w += acc[4*q+3];
            y4[q] = t;
        }
    } else {
#pragma unroll
        for (int c = 0; c < CC; ++c) atomicAdd(yp + c, acc[c]);
    }
}

// ---------------- fused edge kernel: 4 sorted edges/thread, wave seg-reduce ----------------
__global__ __launch_bounds__(256) void k_msg(
    const unsigned int* __restrict__ rec, const int* __restrict__ offs,
    const __half* __restrict__ P0h, const __half* __restrict__ PXh,
    const __half2* __restrict__ whf, const __half2* __restrict__ whs,
    float* __restrict__ y)
{
    int t = blockIdx.x * 256 + threadIdx.x;
    int i0 = t * 4;
    if (i0 >= EE) return;               // whole-wave uniform exit (EE/4 % 64 == 0)
    int lane = threadIdx.x & 63;
    int W = i0 & ~255;                  // wave's first sorted-edge index

    float trail[CC], lead[CC], m[CC];
    int trail_d, lead_d = -1;

    edge_msg(i0, trail_d, rec, P0h, PXh, whf, whs, trail);
#pragma unroll
    for (int j = 1; j < 4; ++j) {
        int dj;
        edge_msg(i0 + j, dj, rec, P0h, PXh, whf, whs, m);
        if (dj == trail_d) {
#pragma unroll
            for (int c = 0; c < CC; ++c) trail[c] += m[c];
        } else {
            if (lead_d < 0) {
#pragma unroll
                for (int c = 0; c < CC; ++c) lead[c] = trail[c];
                lead_d = trail_d;
            } else {
                commit(y, trail_d, trail, true);   // run fully inside thread
            }
#pragma unroll
            for (int c = 0; c < CC; ++c) trail[c] = m[c];
            trail_d = dj;
        }
    }

    // segmented inclusive scan of trail across lanes (d monotone -> simple pred)
    float mk[6];
#pragma unroll
    for (int k = 0; k < 6; ++k) {
        int off = 1 << k;
        int dfrom = __shfl_up(trail_d, off);
        mk[k] = (lane >= off && dfrom == trail_d) ? 1.0f : 0.0f;
    }
#pragma unroll
    for (int k = 0; k < 6; ++k) {
        int off = 1 << k;
#pragma unroll
        for (int c = 0; c < CC; ++c) {
            float tt = __shfl_up(trail[c], off);
            trail[c] = fmaf(tt, mk[k], trail[c]);
        }
    }
    int dt_next = __shfl_down(trail_d, 1);
    int ld_next = __shfl_down(lead_d, 1);
    int d_prev = __shfl_up(trail_d, 1);
    float gate = (lane > 0 && d_prev == lead_d) ? 1.0f : 0.0f;
#pragma unroll
    for (int c = 0; c < CC; ++c) {
        float tt = __shfl_up(trail[c], 1);
        lead[c] = fmaf(tt, gate, lead[c]);
    }

    bool tail = (lane == 63) || (dt_next != trail_d && ld_next != trail_d);
    if (tail) {
        int o0 = offs[trail_d], o1 = offs[trail_d + 1];
        bool complete = (o0 >= W) && (o1 == i0 + 4);
        commit(y, trail_d, trail, complete);
    }
    if (lead_d >= 0) {
        int o0 = offs[lead_d];
        commit(y, lead_d, lead, o0 >= W);   // run ends mid-thread -> within wave
    }
}

// ---------------- BN stats: grid-stride, block-level reduction ----------------
#define STAT_BLOCKS 128
__global__ __launch_bounds__(256) void k_bnstats(const float* __restrict__ y,
                                                 float* __restrict__ sums)
{
    __shared__ float ls[4][2 * CC];
    float s0[CC], s1[CC];
#pragma unroll
    for (int c = 0; c < CC; ++c) { s0[c] = 0.0f; s1[c] = 0.0f; }
    for (int n = blockIdx.x * 256 + threadIdx.x; n < NN; n += STAT_BLOCKS * 256) {
        const float4* p = reinterpret_cast<const float4*>(y + (size_t)n * CC);
#pragma unroll
        for (int q = 0; q < 5; ++q) {
            float4 t = p[q];
            s0[4*q+0] += t.x; s1[4*q+0] += t.x * t.x;
            s0[4*q+1] += t.y; s1[4*q+1] += t.y * t.y;
            s0[4*q+2] += t.z; s1[4*q+2] += t.z * t.z;
            s0[4*q+3] += t.w; s1[4*q+3] += t.w * t.w;
        }
    }
    int lane = threadIdx.x & 63;
    int wave = threadIdx.x >> 6;
#pragma unroll
    for (int c = 0; c < CC; ++c) {
        float a = s0[c], b = s1[c];
        for (int o = 32; o > 0; o >>= 1) {
            a += __shfl_down(a, o);
            b += __shfl_down(b, o);
        }
        if (lane == 0) { ls[wave][c] = a; ls[wave][CC + c] = b; }
    }
    __syncthreads();
    if (threadIdx.x < 2 * CC) {
        float tot = ls[0][threadIdx.x] + ls[1][threadIdx.x] +
                    ls[2][threadIdx.x] + ls[3][threadIdx.x];
        atomicAdd(&sums[threadIdx.x], tot);
    }
}

// ---------------- final: BN + tanh + pool via wave segmented scan ----------------
__global__ __launch_bounds__(256) void k_bnpool(
    const float* __restrict__ y, const float* __restrict__ sums,
    const float* __restrict__ gam, const float* __restrict__ bet,
    const int* __restrict__ batch, float* __restrict__ pooled)
{
    int n = blockIdx.x * 256 + threadIdx.x;
    int nc = n < NN ? n : NN - 1;
    bool valid = n < NN;
    int g = batch[nc];                 // pad lanes: g of last node, v = 0
    const float inv = 1.0f / (float)NN;
    float v[CC];
    const float4* p = reinterpret_cast<const float4*>(y + (size_t)nc * CC);
#pragma unroll
    for (int q = 0; q < 5; ++q) {
        float4 t = p[q];
        v[4*q+0] = t.x; v[4*q+1] = t.y; v[4*q+2] = t.z; v[4*q+3] = t.w;
    }
#pragma unroll
    for (int c = 0; c < CC; ++c) {
        float mean = sums[c] * inv;
        float var  = sums[CC + c] * inv - mean * mean;
        float scale = gam[c] * rsqrtf(var + EPSV);
        float shift = bet[c] - mean * scale;
        v[c] = tanhf(fmaf(v[c], scale, shift));
        if (!valid) v[c] = 0.0f;
    }
    // segmented inclusive scan across the wave keyed by g (batch sorted)
    int lane = threadIdx.x & 63;
    float mk[6];
#pragma unroll
    for (int k = 0; k < 6; ++k) {
        int off = 1 << k;
        int gfrom = __shfl_up(g, off);
        mk[k] = (lane >= off && gfrom == g) ? 1.0f : 0.0f;
    }
#pragma unroll
    for (int k = 0; k < 6; ++k) {
        int off = 1 << k;
#pragma unroll
        for (int c = 0; c < CC; ++c) {
            float tt = __shfl_up(v[c], off);
            v[c] = fmaf(tt, mk[k], v[c]);
        }
    }
    int g_next = __shfl_down(g, 1);
    bool tail = (lane == 63) || (g_next != g);
    if (tail) {
#pragma unroll
        for (int c = 0; c < CC; ++c)
            atomicAdd(&pooled[(size_t)g * CC + c], v[c]);
    }
}

// ---------------- final MLP ----------------
__global__ __launch_bounds__(256) void k_mlp(const float* __restrict__ pooled,
    const float* __restrict__ w1, const float* __restrict__ b1,
    const float* __restrict__ w2, const float* __restrict__ b2,
    const float* __restrict__ w3, const float* __restrict__ b3,
    float* __restrict__ out)
{
    int gi = blockIdx.x * 256 + threadIdx.x;
    if (gi >= GG) return;

    float p[CC];
    const float4* pp = reinterpret_cast<const float4*>(pooled + (size_t)gi * CC);
#pragma unroll
    for (int q = 0; q < 5; ++q) {
        float4 t = pp[q];
        p[4*q+0] = t.x; p[4*q+1] = t.y; p[4*q+2] = t.z; p[4*q+3] = t.w;
    }
    float h1[32];
#pragma unroll
    for (int j = 0; j < 32; ++j) h1[j] = b1[j];
#pragma unroll
    for (int c = 0; c < CC; ++c) {
        float pc = p[c];
#pragma unroll
        for (int j = 0; j < 32; ++j) h1[j] = fmaf(pc, w1[c*32 + j], h1[j]);
    }
#pragma unroll
    for (int j = 0; j < 32; ++j) h1[j] = tanhf(h1[j]);
    float h2[8];
#pragma unroll
    for (int j = 0; j < 8; ++j) h2[j] = b2[j];
#pragma unroll
    for (int c = 0; c < 32; ++c) {
        float hc = h1[c];
#pragma unroll
        for (int j = 0; j < 8; ++j) h2[j] = fmaf(hc, w2[c*8 + j], h2[j]);
    }
    float o = b3[0];
#pragma unroll
    for (int j = 0; j < 8; ++j) o = fmaf(tanhf(h2[j]), w3[j], o);
    out[gi] = o;
}

extern "C" void kernel_launch(void* const* d_in, const int* in_sizes, int n_in,
                              void* d_out, int out_size, void* d_ws, size_t ws_size,
                              hipStream_t stream) {
    const float* x   = (const float*)d_in[0];
    const int*   ei  = (const int*)d_in[1];
    const float* ea  = (const float*)d_in[2];
    const int*   bat = (const int*)d_in[3];
    const float* lfw = (const float*)d_in[4];
    const float* lfb = (const float*)d_in[5];
    const float* lsw = (const float*)d_in[6];
    const float* lsb = (const float*)d_in[7];
    const float* bng = (const float*)d_in[8];
    const float* bnb = (const float*)d_in[9];
    const float* w1  = (const float*)d_in[10];
    const float* b1  = (const float*)d_in[11];
    const float* w2  = (const float*)d_in[12];
    const float* b2  = (const float*)d_in[13];
    const float* w3  = (const float*)d_in[14];
    const float* b3  = (const float*)d_in[15];
    float* out = (float*)d_out;

    char* ws = (char*)d_ws;
    float*        y      = (float*)ws;                          // NN*CC f    (8 MB)
    __half*       P0h    = (__half*)(y + (size_t)NN * CC);      // NN*2CC h   (8 MB)
    __half*       PXh    = P0h + (size_t)NN * 2 * CC;           // NN*2CC h   (8 MB)
    unsigned int* rec    = (unsigned int*)(PXh + (size_t)NN * 2 * CC); // EE*8 u (51.2 MB)
    int*          offs   = (int*)(rec + (size_t)EE * RSTRIDE);  // NPAD
    int*          cur2   = offs + NPAD;                         // NPAD (written by scan_bc)
    __half2*      wtab   = (__half2*)(cur2 + NPAD);             // 320 half2 = 640 B
    int*          bsum   = (int*)(wtab + 320);                  // 256
    // zeroed region starts here:
    int*          cnt    = bsum + 256;                          // NN
    float*        sums   = (float*)(cnt + NN);                  // 2 layers * 2*CC
    float*        pooled = sums + 2 * 2 * CC;                   // GG*CC

    size_t zbytes = ((size_t)NN + 2*2*CC + (size_t)GG*CC) * sizeof(int);
    hipMemsetAsync(cnt, 0, zbytes, stream);

    // ---- CSR build + fused record scatter / pre0 ----
    k_hist<<<(EE/4 + 255) / 256, 256, 0, stream>>>(ei, cnt, lfw, lsw, wtab);
    k_scan_a<<<NB, SCAN_TPB, 0, stream>>>(cnt, offs, bsum);
    k_scan_bc<<<NPAD / 256, 256, 0, stream>>>(offs, bsum, cur2);
    k_rec<<<RBLK + NBLK, 256, 0, stream>>>(ei, ea, cur2, rec,
                                           x, lfw, lfb, lsw, lsb, P0h, PXh, y);

    const int nblocks = (NN + 255) / 256;
    const int mblocks = (EE / 4 + 255) / 256;   // 1563

    // layer 0
    k_msg<<<mblocks, 256, 0, stream>>>(rec, offs, P0h, PXh,
                                       wtab, wtab + 80, y);
    k_bnstats<<<STAT_BLOCKS, 256, 0, stream>>>(y, sums);
    // BN(l0)+tanh in place, precompute P0h/PXh for layer 1
    k_bnpre<<<nblocks, 256, 0, stream>>>(y, sums, bng, bnb,
        lfw + (size_t)KK*CC, lfb + CC, lsw + (size_t)KK*CC, lsb + CC, P0h, PXh);
    // layer 1
    k_msg<<<mblocks, 256, 0, stream>>>(rec, offs, P0h, PXh,
        wtab + 160, wtab + 240, y);
    k_bnstats<<<STAT_BLOCKS, 256, 0, stream>>>(y, sums + 2*CC);
    // BN(l1)+tanh+pool
    k_bnpool<<<nblocks, 256, 0, stream>>>(y, sums + 2*CC, bng + CC, bnb + CC,
                                          bat, pooled);
    k_mlp<<<(GG + 255) / 256, 256, 0, stream>>>(pooled, w1, b1, w2, b2, w3, b3, out);
}

// Round 18
// 414.227 us; speedup vs baseline: 1.4089x; 1.0534x over previous
//
#include <hip/hip_runtime.h>
#include <hip/hip_fp16.h>
#include <math.h>

#define NN 100000
#define EE 1600000
#define CC 20
#define DD 8
#define GG 1024
#define LL 2
#define KK (2*CC+DD)   // 48
#define EPSV 1e-5f

#define SCAN_TPB 256
#define SCAN_ELEMS 4
#define NB 98                      // ceil(NN / 1024)
#define NPAD (NB * SCAN_TPB * SCAN_ELEMS)  // 100352
#define RSTRIDE 8                  // record = 8 dwords = 32 B {s,d, 8×half, pad}
#define RBLK 6250                  // ceil(EE/256) edge blocks in fused k_rec
#define NBLK 391                   // ceil(NN/256) node blocks

union H2U { __half2 h; unsigned int u; };

// native clang vector types for nontemporal builtins (HIP float4/int4 are rejected)
typedef float nf4 __attribute__((ext_vector_type(4)));
typedef int   ni4 __attribute__((ext_vector_type(4)));

__device__ __forceinline__ float4 ntload_f4(const float* p) {
    nf4 v = __builtin_nontemporal_load(reinterpret_cast<const nf4*>(p));
    return make_float4(v.x, v.y, v.z, v.w);
}

// ---- helper: pack 2*CC floats -> 20 half2 words and store as 5 uint4 ----
__device__ __forceinline__ void store_h40(__half* dstp,
                                          const float* fx, const float* gx) {
    unsigned int w[20];
#pragma unroll
    for (int j = 0; j < 10; ++j) {
        H2U cv; cv.h = __floats2half2_rn(fx[2*j], fx[2*j+1]);
        w[j] = cv.u;
    }
#pragma unroll
    for (int j = 0; j < 10; ++j) {
        H2U cv; cv.h = __floats2half2_rn(gx[2*j], gx[2*j+1]);
        w[10 + j] = cv.u;
    }
    uint4* d4 = reinterpret_cast<uint4*>(dstp);
#pragma unroll
    for (int i = 0; i < 5; ++i)
        d4[i] = make_uint4(w[4*i], w[4*i+1], w[4*i+2], w[4*i+3]);
}

// ---------------- CSR build: histogram + per-edge rank (atomic return value)
//                  block 0 also builds the fp16 weight table ----------------
__global__ __launch_bounds__(256) void k_hist(const int* __restrict__ ei,
                                              int* __restrict__ cnt,
                                              int* __restrict__ rank,
                                              const float* __restrict__ lfw,
                                              const float* __restrict__ lsw,
                                              __half2* __restrict__ wtab) {
    if (blockIdx.x == 0) {
        for (int t = threadIdx.x; t < 320; t += 256) {
            int l   = t / 160;
            int mat = (t / 80) & 1;
            int k   = (t / 10) % 8;
            int j   = t % 10;
            const float* src = (mat ? lsw : lfw) + (size_t)l * KK * CC + (2*CC + k) * CC + 2*j;
            wtab[t] = __floats2half2_rn(src[0], src[1]);
        }
    }
    int t = blockIdx.x * 256 + threadIdx.x;
    if (t * 4 >= EE) return;
    ni4 d4 = __builtin_nontemporal_load(reinterpret_cast<const ni4*>(ei + EE) + t);
    int4 r4;
    r4.x = atomicAdd(&cnt[d4.x], 1);
    r4.y = atomicAdd(&cnt[d4.y], 1);
    r4.z = atomicAdd(&cnt[d4.z], 1);
    r4.w = atomicAdd(&cnt[d4.w], 1);
    reinterpret_cast<int4*>(rank)[t] = r4;   // coalesced
}

__global__ __launch_bounds__(SCAN_TPB) void k_scan_a(const int* __restrict__ cnt,
                                                     int* __restrict__ offs,
                                                     int* __restrict__ bsum) {
    __shared__ int sdata[SCAN_TPB];
    int base = blockIdx.x * (SCAN_TPB * SCAN_ELEMS) + threadIdx.x * SCAN_ELEMS;
    int v[SCAN_ELEMS];
    int tot = 0;
#pragma unroll
    for (int i = 0; i < SCAN_ELEMS; ++i) {
        int idx = base + i;
        v[i] = (idx < NN) ? cnt[idx] : 0;
        tot += v[i];
    }
    sdata[threadIdx.x] = tot;
    __syncthreads();
    for (int o = 1; o < SCAN_TPB; o <<= 1) {
        int t = (threadIdx.x >= o) ? sdata[threadIdx.x - o] : 0;
        __syncthreads();
        sdata[threadIdx.x] += t;
        __syncthreads();
    }
    int run = sdata[threadIdx.x] - tot;  // exclusive prefix of this thread
#pragma unroll
    for (int i = 0; i < SCAN_ELEMS; ++i) {
        offs[base + i] = run;
        run += v[i];
    }
    if (threadIdx.x == SCAN_TPB - 1) bsum[blockIdx.x] = sdata[threadIdx.x];
}

// scan of bsum (redundant per block) + add to offs
__global__ __launch_bounds__(256) void k_scan_bc(int* __restrict__ offs,
                                                 const int* __restrict__ bsum) {
    __shared__ int sv[SCAN_TPB];
    __shared__ int se[SCAN_TPB];
    int v = (threadIdx.x < NB) ? bsum[threadIdx.x] : 0;
    sv[threadIdx.x] = v;
    __syncthreads();
    for (int o = 1; o < SCAN_TPB; o <<= 1) {
        int t = (threadIdx.x >= o) ? sv[threadIdx.x - o] : 0;
        __syncthreads();
        sv[threadIdx.x] += t;
        __syncthreads();
    }
    se[threadIdx.x] = sv[threadIdx.x] - v;   // exclusive
    __syncthreads();
    int i = blockIdx.x * 256 + threadIdx.x;  // grid = NPAD/256 exactly
    offs[i] += se[blockIdx.x >> 2];          // (i>>10) constant per block
}

// ---- fused: record scatter (blocks < RBLK) + per-node precompute (blocks >= RBLK)
// scatter uses precomputed rank: pos = offs[d] + rank[e] (no atomic in chain) ----
__global__ __launch_bounds__(256) void k_rec(const int* __restrict__ ei,
                                             const float* __restrict__ ea,
                                             const int* __restrict__ rank,
                                             const int* __restrict__ offs,
                                             unsigned int* __restrict__ rec,
                                             const float* __restrict__ x,
                                             const float* __restrict__ wf,
                                             const float* __restrict__ bf,
                                             const float* __restrict__ wsm,
                                             const float* __restrict__ bs,
                                             __half* __restrict__ P0h,
                                             __half* __restrict__ PXh,
                                             float* __restrict__ y) {
    if (blockIdx.x >= RBLK) {
        // ---- pre0 part ----
        int n = (blockIdx.x - RBLK) * 256 + threadIdx.x;
        if (n >= NN) return;
        float xn[CC];
        const float4* xp = reinterpret_cast<const float4*>(x + (size_t)n * CC);
        float4* yp = reinterpret_cast<float4*>(y + (size_t)n * CC);
#pragma unroll
        for (int q = 0; q < 5; ++q) {
            float4 t = xp[q];
            yp[q] = t;
            xn[4*q+0] = t.x; xn[4*q+1] = t.y; xn[4*q+2] = t.z; xn[4*q+3] = t.w;
        }
        float f0[CC], g0[CC], fx[CC], gx[CC];
#pragma unroll
        for (int c = 0; c < CC; ++c) { f0[c] = bf[c]; g0[c] = bs[c]; fx[c] = 0.f; gx[c] = 0.f; }
#pragma unroll
        for (int k = 0; k < CC; ++k) {
            float zk = xn[k];
#pragma unroll
            for (int c = 0; c < CC; ++c) {
                f0[c] = fmaf(zk, wf[k*CC + c], f0[c]);
                g0[c] = fmaf(zk, wsm[k*CC + c], g0[c]);
                fx[c] = fmaf(zk, wf[(CC+k)*CC + c], fx[c]);
                gx[c] = fmaf(zk, wsm[(CC+k)*CC + c], gx[c]);
            }
        }
        store_h40(P0h + (size_t)n * 2*CC, f0, g0);
        store_h40(PXh + (size_t)n * 2*CC, fx, gx);
        return;
    }
    // ---- record scatter part (atomic-free) ----
    int e = blockIdx.x * 256 + threadIdx.x;
    if (e >= EE) return;
    int s = __builtin_nontemporal_load(ei + e);
    int d = __builtin_nontemporal_load(ei + EE + e);
    int r = __builtin_nontemporal_load(rank + e);
    int pos = offs[d] + r;                   // offs: 400 KB, L2-resident gather
    float4 a = ntload_f4(ea + (size_t)e * DD);
    float4 b = ntload_f4(ea + (size_t)e * DD + 4);
    H2U h01; h01.h = __floats2half2_rn(a.x, a.y);
    H2U h23; h23.h = __floats2half2_rn(a.z, a.w);
    H2U h45; h45.h = __floats2half2_rn(b.x, b.y);
    H2U h67; h67.h = __floats2half2_rn(b.z, b.w);
    uint4* dst = reinterpret_cast<uint4*>(rec + (size_t)pos * RSTRIDE);
    dst[0] = make_uint4((unsigned int)s, (unsigned int)d, h01.u, h23.u);
    dst[1] = make_uint4(h45.u, h67.u, 0u, 0u);
}

// ---------------- BN(prev layer) + tanh in place, then P0h/PXh for next layer
__global__ __launch_bounds__(256) void k_bnpre(
    float* __restrict__ y, const float* __restrict__ sums,
    const float* __restrict__ gam, const float* __restrict__ bet,
    const float* __restrict__ wf, const float* __restrict__ bf,
    const float* __restrict__ wsm, const float* __restrict__ bs,
    __half* __restrict__ P0h, __half* __restrict__ PXh)
{
    int n = blockIdx.x * 256 + threadIdx.x;
    if (n >= NN) return;
    const float inv = 1.0f / (float)NN;
    float4* yp = reinterpret_cast<float4*>(y + (size_t)n * CC);
    float xn[CC];
#pragma unroll
    for (int q = 0; q < 5; ++q) {
        float4 t = yp[q];
        xn[4*q+0] = t.x; xn[4*q+1] = t.y; xn[4*q+2] = t.z; xn[4*q+3] = t.w;
    }
#pragma unroll
    for (int c = 0; c < CC; ++c) {
        float mean = sums[c] * inv;
        float var  = sums[CC + c] * inv - mean * mean;
        float scale = gam[c] * rsqrtf(var + EPSV);
        float shift = bet[c] - mean * scale;
        xn[c] = tanhf(fmaf(xn[c], scale, shift));
    }
#pragma unroll
    for (int q = 0; q < 5; ++q)
        yp[q] = make_float4(xn[4*q+0], xn[4*q+1], xn[4*q+2], xn[4*q+3]);

    float f0[CC], g0[CC], fx[CC], gx[CC];
#pragma unroll
    for (int c = 0; c < CC; ++c) { f0[c] = bf[c]; g0[c] = bs[c]; fx[c] = 0.f; gx[c] = 0.f; }
#pragma unroll
    for (int k = 0; k < CC; ++k) {
        float zk = xn[k];
#pragma unroll
        for (int c = 0; c < CC; ++c) {
            f0[c] = fmaf(zk, wf[k*CC + c], f0[c]);
            g0[c] = fmaf(zk, wsm[k*CC + c], g0[c]);
            fx[c] = fmaf(zk, wf[(CC+k)*CC + c], fx[c]);
            gx[c] = fmaf(zk, wsm[(CC+k)*CC + c], gx[c]);
        }
    }
    store_h40(P0h + (size_t)n * 2*CC, f0, g0);
    store_h40(PXh + (size_t)n * 2*CC, fx, gx);
}

// ---------------- edge message: packed fp16 GEMM ----------------
__device__ __forceinline__ void edge_msg(int i, int& d_out,
    const unsigned int* __restrict__ rec, const __half* __restrict__ P0h,
    const __half* __restrict__ PXh,
    const __half2* __restrict__ whf, const __half2* __restrict__ whs,
    float* m)
{
    const uint4* rp = reinterpret_cast<const uint4*>(rec + (size_t)i * RSTRIDE);
    uint4 r0 = rp[0], r1 = rp[1];
    int s = (int)r0.x;
    int d = (int)r0.y;
    d_out = d;
    __half2 ebc[8];
    {
        H2U a; a.u = r0.z;
        ebc[0] = __low2half2(a.h);  ebc[1] = __high2half2(a.h);
        H2U b; b.u = r0.w;
        ebc[2] = __low2half2(b.h);  ebc[3] = __high2half2(b.h);
        H2U c; c.u = r1.x;
        ebc[4] = __low2half2(c.h);  ebc[5] = __high2half2(c.h);
        H2U e; e.u = r1.y;
        ebc[6] = __low2half2(e.h);  ebc[7] = __high2half2(e.h);
    }

    const uint4* pxp = reinterpret_cast<const uint4*>(PXh + (size_t)s * 2*CC);
    const uint4* p0p = reinterpret_cast<const uint4*>(P0h + (size_t)d * 2*CC);
    uint4 x0 = pxp[0], x1 = pxp[1], x2 = pxp[2], x3 = pxp[3], x4 = pxp[4];
    uint4 z0 = p0p[0], z1 = p0p[1], z2 = p0p[2], z3 = p0p[3], z4 = p0p[4];
    unsigned int xw[20] = {x0.x, x0.y, x0.z, x0.w, x1.x, x1.y, x1.z, x1.w,
                           x2.x, x2.y, x2.z, x2.w, x3.x, x3.y, x3.z, x3.w,
                           x4.x, x4.y, x4.z, x4.w};
    unsigned int zw[20] = {z0.x, z0.y, z0.z, z0.w, z1.x, z1.y, z1.z, z1.w,
                           z2.x, z2.y, z2.z, z2.w, z3.x, z3.y, z3.z, z3.w,
                           z4.x, z4.y, z4.z, z4.w};
    __half2 fh[10], gh[10];
#pragma unroll
    for (int j = 0; j < 10; ++j) {
        H2U a; a.u = xw[j];
        H2U b; b.u = zw[j];
        fh[j] = __hadd2(a.h, b.h);
    }
#pragma unroll
    for (int j = 0; j < 10; ++j) {
        H2U a; a.u = xw[10 + j];
        H2U b; b.u = zw[10 + j];
        gh[j] = __hadd2(a.h, b.h);
    }
    // edge-attr GEMM in packed fp16: rows 2CC..KK-1
#pragma unroll
    for (int k = 0; k < 8; ++k) {
        __half2 bc = ebc[k];
#pragma unroll
        for (int j = 0; j < 10; ++j) {
            fh[j] = __hfma2(bc, whf[k*10 + j], fh[j]);
            gh[j] = __hfma2(bc, whs[k*10 + j], gh[j]);
        }
    }
#pragma unroll
    for (int j = 0; j < 10; ++j) {
        float2 ff = __half22float2(fh[j]);
        float2 gg = __half22float2(gh[j]);
        float sg0 = 1.0f / (1.0f + __expf(-ff.x));
        float sg1 = 1.0f / (1.0f + __expf(-ff.y));
        float sp0 = fmaxf(gg.x, 0.0f) + __logf(1.0f + __expf(-fabsf(gg.x)));
        float sp1 = fmaxf(gg.y, 0.0f) + __logf(1.0f + __expf(-fabsf(gg.y)));
        m[2*j]   = sg0 * sp0;
        m[2*j+1] = sg1 * sp1;
    }
}

__device__ __forceinline__ void commit(float* __restrict__ y, int d,
                                       const float* acc, bool complete) {
    float* yp = y + (size_t)d * CC;
    if (complete) {
        float4* y4 = reinterpret_cast<float4*>(yp);
#pragma unroll
        for (int q = 0; q < 5; ++q) {
            float4 t = y4[q];
            t.x += acc[4*q+0]; t.y += acc[4*q+1];
            t.z += acc[4*q+2]; t.w += acc[4*q+3];
            y4[q] = t;
        }
    } else {
#pragma unroll
        for (int c = 0; c < CC; ++c) atomicAdd(yp + c, acc[c]);
    }
}

// ---------------- fused edge kernel: 4 sorted edges/thread, wave seg-reduce ----------------
__global__ __launch_bounds__(256) void k_msg(
    const unsigned int* __restrict__ rec, const int* __restrict__ offs,
    const __half* __restrict__ P0h, const __half* __restrict__ PXh,
    const __half2* __restrict__ whf, const __half2* __restrict__ whs,
    float* __restrict__ y)
{
    int t = blockIdx.x * 256 + threadIdx.x;
    int i0 = t * 4;
    if (i0 >= EE) return;               // whole-wave uniform exit (EE/4 % 64 == 0)
    int lane = threadIdx.x & 63;
    int W = i0 & ~255;                  // wave's first sorted-edge index

    float trail[CC], lead[CC], m[CC];
    int trail_d, lead_d = -1;

    edge_msg(i0, trail_d, rec, P0h, PXh, whf, whs, trail);
#pragma unroll
    for (int j = 1; j < 4; ++j) {
        int dj;
        edge_msg(i0 + j, dj, rec, P0h, PXh, whf, whs, m);
        if (dj == trail_d) {
#pragma unroll
            for (int c = 0; c < CC; ++c) trail[c] += m[c];
        } else {
            if (lead_d < 0) {
#pragma unroll
                for (int c = 0; c < CC; ++c) lead[c] = trail[c];
                lead_d = trail_d;
            } else {
                commit(y, trail_d, trail, true);   // run fully inside thread
            }
#pragma unroll
            for (int c = 0; c < CC; ++c) trail[c] = m[c];
            trail_d = dj;
        }
    }

    // segmented inclusive scan of trail across lanes (d monotone -> simple pred)
    float mk[6];
#pragma unroll
    for (int k = 0; k < 6; ++k) {
        int off = 1 << k;
        int dfrom = __shfl_up(trail_d, off);
        mk[k] = (lane >= off && dfrom == trail_d) ? 1.0f : 0.0f;
    }
#pragma unroll
    for (int k = 0; k < 6; ++k) {
        int off = 1 << k;
#pragma unroll
        for (int c = 0; c < CC; ++c) {
            float tt = __shfl_up(trail[c], off);
            trail[c] = fmaf(tt, mk[k], trail[c]);
        }
    }
    int dt_next = __shfl_down(trail_d, 1);
    int ld_next = __shfl_down(lead_d, 1);
    int d_prev = __shfl_up(trail_d, 1);
    float gate = (lane > 0 && d_prev == lead_d) ? 1.0f : 0.0f;
#pragma unroll
    for (int c = 0; c < CC; ++c) {
        float tt = __shfl_up(trail[c], 1);
        lead[c] = fmaf(tt, gate, lead[c]);
    }

    bool tail = (lane == 63) || (dt_next != trail_d && ld_next != trail_d);
    if (tail) {
        int o0 = offs[trail_d], o1 = offs[trail_d + 1];
        bool complete = (o0 >= W) && (o1 == i0 + 4);
        commit(y, trail_d, trail, complete);
    }
    if (lead_d >= 0) {
        int o0 = offs[lead_d];
        commit(y, lead_d, lead, o0 >= W);   // run ends mid-thread -> within wave
    }
}

// ---------------- BN stats: grid-stride, block-level reduction ----------------
#define STAT_BLOCKS 128
__global__ __launch_bounds__(256) void k_bnstats(const float* __restrict__ y,
                                                 float* __restrict__ sums)
{
    __shared__ float ls[4][2 * CC];
    float s0[CC], s1[CC];
#pragma unroll
    for (int c = 0; c < CC; ++c) { s0[c] = 0.0f; s1[c] = 0.0f; }
    for (int n = blockIdx.x * 256 + threadIdx.x; n < NN; n += STAT_BLOCKS * 256) {
        const float4* p = reinterpret_cast<const float4*>(y + (size_t)n * CC);
#pragma unroll
        for (int q = 0; q < 5; ++q) {
            float4 t = p[q];
            s0[4*q+0] += t.x; s1[4*q+0] += t.x * t.x;
            s0[4*q+1] += t.y; s1[4*q+1] += t.y * t.y;
            s0[4*q+2] += t.z; s1[4*q+2] += t.z * t.z;
            s0[4*q+3] += t.w; s1[4*q+3] += t.w * t.w;
        }
    }
    int lane = threadIdx.x & 63;
    int wave = threadIdx.x >> 6;
#pragma unroll
    for (int c = 0; c < CC; ++c) {
        float a = s0[c], b = s1[c];
        for (int o = 32; o > 0; o >>= 1) {
            a += __shfl_down(a, o);
            b += __shfl_down(b, o);
        }
        if (lane == 0) { ls[wave][c] = a; ls[wave][CC + c] = b; }
    }
    __syncthreads();
    if (threadIdx.x < 2 * CC) {
        float tot = ls[0][threadIdx.x] + ls[1][threadIdx.x] +
                    ls[2][threadIdx.x] + ls[3][threadIdx.x];
        atomicAdd(&sums[threadIdx.x], tot);
    }
}

// ---------------- final: BN + tanh + pool via wave segmented scan ----------------
__global__ __launch_bounds__(256) void k_bnpool(
    const float* __restrict__ y, const float* __restrict__ sums,
    const float* __restrict__ gam, const float* __restrict__ bet,
    const int* __restrict__ batch, float* __restrict__ pooled)
{
    int n = blockIdx.x * 256 + threadIdx.x;
    int nc = n < NN ? n : NN - 1;
    bool valid = n < NN;
    int g = batch[nc];                 // pad lanes: g of last node, v = 0
    const float inv = 1.0f / (float)NN;
    float v[CC];
    const float4* p = reinterpret_cast<const float4*>(y + (size_t)nc * CC);
#pragma unroll
    for (int q = 0; q < 5; ++q) {
        float4 t = p[q];
        v[4*q+0] = t.x; v[4*q+1] = t.y; v[4*q+2] = t.z; v[4*q+3] = t.w;
    }
#pragma unroll
    for (int c = 0; c < CC; ++c) {
        float mean = sums[c] * inv;
        float var  = sums[CC + c] * inv - mean * mean;
        float scale = gam[c] * rsqrtf(var + EPSV);
        float shift = bet[c] - mean * scale;
        v[c] = tanhf(fmaf(v[c], scale, shift));
        if (!valid) v[c] = 0.0f;
    }
    // segmented inclusive scan across the wave keyed by g (batch sorted)
    int lane = threadIdx.x & 63;
    float mk[6];
#pragma unroll
    for (int k = 0; k < 6; ++k) {
        int off = 1 << k;
        int gfrom = __shfl_up(g, off);
        mk[k] = (lane >= off && gfrom == g) ? 1.0f : 0.0f;
    }
#pragma unroll
    for (int k = 0; k < 6; ++k) {
        int off = 1 << k;
#pragma unroll
        for (int c = 0; c < CC; ++c) {
            float tt = __shfl_up(v[c], off);
            v[c] = fmaf(tt, mk[k], v[c]);
        }
    }
    int g_next = __shfl_down(g, 1);
    bool tail = (lane == 63) || (g_next != g);
    if (tail) {
#pragma unroll
        for (int c = 0; c < CC; ++c)
            atomicAdd(&pooled[(size_t)g * CC + c], v[c]);
    }
}

// ---------------- final MLP ----------------
__global__ __launch_bounds__(256) void k_mlp(const float* __restrict__ pooled,
    const float* __restrict__ w1, const float* __restrict__ b1,
    const float* __restrict__ w2, const float* __restrict__ b2,
    const float* __restrict__ w3, const float* __restrict__ b3,
    float* __restrict__ out)
{
    int gi = blockIdx.x * 256 + threadIdx.x;
    if (gi >= GG) return;

    float p[CC];
    const float4* pp = reinterpret_cast<const float4*>(pooled + (size_t)gi * CC);
#pragma unroll
    for (int q = 0; q < 5; ++q) {
        float4 t = pp[q];
        p[4*q+0] = t.x; p[4*q+1] = t.y; p[4*q+2] = t.z; p[4*q+3] = t.w;
    }
    float h1[32];
#pragma unroll
    for (int j = 0; j < 32; ++j) h1[j] = b1[j];
#pragma unroll
    for (int c = 0; c < CC; ++c) {
        float pc = p[c];
#pragma unroll
        for (int j = 0; j < 32; ++j) h1[j] = fmaf(pc, w1[c*32 + j], h1[j]);
    }
#pragma unroll
    for (int j = 0; j < 32; ++j) h1[j] = tanhf(h1[j]);
    float h2[8];
#pragma unroll
    for (int j = 0; j < 8; ++j) h2[j] = b2[j];
#pragma unroll
    for (int c = 0; c < 32; ++c) {
        float hc = h1[c];
#pragma unroll
        for (int j = 0; j < 8; ++j) h2[j] = fmaf(hc, w2[c*8 + j], h2[j]);
    }
    float o = b3[0];
#pragma unroll
    for (int j = 0; j < 8; ++j) o = fmaf(tanhf(h2[j]), w3[j], o);
    out[gi] = o;
}

extern "C" void kernel_launch(void* const* d_in, const int* in_sizes, int n_in,
                              void* d_out, int out_size, void* d_ws, size_t ws_size,
                              hipStream_t stream) {
    const float* x   = (const float*)d_in[0];
    const int*   ei  = (const int*)d_in[1];
    const float* ea  = (const float*)d_in[2];
    const int*   bat = (const int*)d_in[3];
    const float* lfw = (const float*)d_in[4];
    const float* lfb = (const float*)d_in[5];
    const float* lsw = (const float*)d_in[6];
    const float* lsb = (const float*)d_in[7];
    const float* bng = (const float*)d_in[8];
    const float* bnb = (const float*)d_in[9];
    const float* w1  = (const float*)d_in[10];
    const float* b1  = (const float*)d_in[11];
    const float* w2  = (const float*)d_in[12];
    const float* b2  = (const float*)d_in[13];
    const float* w3  = (const float*)d_in[14];
    const float* b3  = (const float*)d_in[15];
    float* out = (float*)d_out;

    char* ws = (char*)d_ws;
    float*        y      = (float*)ws;                          // NN*CC f    (8 MB)
    __half*       P0h    = (__half*)(y + (size_t)NN * CC);      // NN*2CC h   (8 MB)
    __half*       PXh    = P0h + (size_t)NN * 2 * CC;           // NN*2CC h   (8 MB)
    unsigned int* rec    = (unsigned int*)(PXh + (size_t)NN * 2 * CC); // EE*8 u (51.2 MB)
    int*          rank   = (int*)(rec + (size_t)EE * RSTRIDE);  // EE ints    (6.4 MB)
    int*          offs   = rank + EE;                           // NPAD
    __half2*      wtab   = (__half2*)(offs + NPAD);             // 320 half2 = 640 B
    int*          bsum   = (int*)(wtab + 320);                  // 256
    // zeroed region starts here:
    int*          cnt    = bsum + 256;                          // NN
    float*        sums   = (float*)(cnt + NN);                  // 2 layers * 2*CC
    float*        pooled = sums + 2 * 2 * CC;                   // GG*CC

    size_t zbytes = ((size_t)NN + 2*2*CC + (size_t)GG*CC) * sizeof(int);
    hipMemsetAsync(cnt, 0, zbytes, stream);

    // ---- CSR build (hist emits per-edge rank) + fused record scatter / pre0 ----
    k_hist<<<(EE/4 + 255) / 256, 256, 0, stream>>>(ei, cnt, rank, lfw, lsw, wtab);
    k_scan_a<<<NB, SCAN_TPB, 0, stream>>>(cnt, offs, bsum);
    k_scan_bc<<<NPAD / 256, 256, 0, stream>>>(offs, bsum);
    k_rec<<<RBLK + NBLK, 256, 0, stream>>>(ei, ea, rank, offs, rec,
                                           x, lfw, lfb, lsw, lsb, P0h, PXh, y);

    const int nblocks = (NN + 255) / 256;
    const int mblocks = (EE / 4 + 255) / 256;   // 1563

    // layer 0
    k_msg<<<mblocks, 256, 0, stream>>>(rec, offs, P0h, PXh,
                                       wtab, wtab + 80, y);
    k_bnstats<<<STAT_BLOCKS, 256, 0, stream>>>(y, sums);
    // BN(l0)+tanh in place, precompute P0h/PXh for layer 1
    k_bnpre<<<nblocks, 256, 0, stream>>>(y, sums, bng, bnb,
        lfw + (size_t)KK*CC, lfb + CC, lsw + (size_t)KK*CC, lsb + CC, P0h, PXh);
    // layer 1
    k_msg<<<mblocks, 256, 0, stream>>>(rec, offs, P0h, PXh,
        wtab + 160, wtab + 240, y);
    k_bnstats<<<STAT_BLOCKS, 256, 0, stream>>>(y, sums + 2*CC);
    // BN(l1)+tanh+pool
    k_bnpool<<<nblocks, 256, 0, stream>>>(y, sums + 2*CC, bng + CC, bnb + CC,
                                          bat, pooled);
    k_mlp<<<(GG + 255) / 256, 256, 0, stream>>>(pooled, w1, b1, w2, b2, w3, b3, out);
}